// Round 1
// baseline (649.881 us; speedup 1.0000x reference)
//
#include <hip/hip_runtime.h>
#include <hip/hip_bf16.h>

// Problem constants (fixed by setup_inputs)
#define NRES   768
#define C_S    256
#define C_P    128
#define FEAT   64
#define NBINS  22
#define NP     129   // padded LDS row stride (floats): (l*129+k)%32 = (l+k)%32 -> 2 lanes/bank (free)

// ---------------------------------------------------------------------------
// bin index for distogram: one-hot over (lower[k] < d < upper[k]),
// lower = linspace(0.001, 20, 22), upper = [lower[1:], 1e8]. -1 => all-zero row.
__device__ __forceinline__ int bin_idx(float d) {
    const float lo0  = 0.001f;
    const float step = (20.0f - 0.001f) / 21.0f;
    int k = (int)floorf((d - lo0) / step);
    if (k < -1) k = -1;
    if (k > 21) k = 21;
    // check candidate and neighbors (bins disjoint; handles float rounding slop)
    for (int kk = k + 1; kk >= k - 1; --kk) {
        if (kk < 0 || kk > 21) continue;
        float lk = lo0 + (float)kk * step;
        float uk = (kk < 21) ? (lo0 + (float)(kk + 1) * step) : 1e8f;
        if (d > lk && d < uk) return kk;
    }
    return -1;
}

// ---------------------------------------------------------------------------
// Per-node precompute: p_i = s@W_sp + b_sp, then
//   A[i][c] = sum_k p[k]*W1[k][c]      + dm[i]*W1[236][c] + b1[c]
//   B[i][c] = sum_k p[k]*W1[64+k][c]   + dm[i]*W1[237][c]
__global__ void node_kernel(const float* __restrict__ s, const float* __restrict__ dm,
                            const float* __restrict__ W_sp, const float* __restrict__ b_sp,
                            const float* __restrict__ W1, const float* __restrict__ b1,
                            float* __restrict__ A, float* __restrict__ Bt) {
    __shared__ float srow[C_S];
    __shared__ float psh[FEAT];
    const int i = blockIdx.x;
    const int t = threadIdx.x;  // 128 threads
    srow[t]       = s[i * C_S + t];
    srow[t + 128] = s[i * C_S + 128 + t];
    __syncthreads();
    if (t < FEAT) {
        float acc = b_sp[t];
        for (int m = 0; m < C_S; ++m) acc = fmaf(srow[m], W_sp[m * FEAT + t], acc);
        psh[t] = acc;
    }
    __syncthreads();
    const float d = dm[i];
    float accA = fmaf(d, W1[236 * C_P + t], b1[t]);
    float accB = d * W1[237 * C_P + t];
    for (int k = 0; k < FEAT; ++k) {
        float p = psh[k];
        accA = fmaf(p, W1[k * C_P + t], accA);
        accB = fmaf(p, W1[(FEAT + k) * C_P + t], accB);
    }
    A[i * C_P + t]  = accA;
    Bt[i * C_P + t] = accB;
}

// ---------------------------------------------------------------------------
// Wcomb[k][c] = sum_m W_rp[k][m] * W1[128+m][c]  (k<64);  row 64 = b_rp @ W1rp
__global__ void wcomb_kernel(const float* __restrict__ W_rp, const float* __restrict__ b_rp,
                             const float* __restrict__ W1, float* __restrict__ Wcomb) {
    const int k = blockIdx.x;   // 0..64
    const int c = threadIdx.x;  // 128
    float acc = 0.0f;
    if (k < FEAT) {
        for (int m = 0; m < FEAT; ++m)
            acc = fmaf(W_rp[k * FEAT + m], W1[(2 * FEAT + m) * C_P + c], acc);
    } else {
        for (int m = 0; m < FEAT; ++m)
            acc = fmaf(b_rp[m], W1[(2 * FEAT + m) * C_P + c], acc);
    }
    Wcomb[k * C_P + c] = acc;
}

// ---------------------------------------------------------------------------
// RP[d+767][c] = sum_k embed(d)[k]*Wcomb[k][c] + Wcomb[64][c]
__global__ void rp_kernel(const float* __restrict__ Wcomb, float* __restrict__ RP) {
    __shared__ float emb[FEAT];
    const int bi = blockIdx.x;            // 0..1534
    const float d = (float)(bi - (NRES - 1));
    const int c = threadIdx.x;            // 128
    if (c < FEAT / 2) {
        float expo = 2.0f * (float)c / (float)FEAT;
        float freq = 3.14159265358979323846f / powf(2056.0f, expo);
        float ang = d * freq;
        emb[c]            = sinf(ang);
        emb[c + FEAT / 2] = cosf(ang);
    }
    __syncthreads();
    float acc = Wcomb[FEAT * C_P + c];
    for (int k = 0; k < FEAT; ++k) acc = fmaf(emb[k], Wcomb[k * C_P + c], acc);
    RP[bi * C_P + c] = acc;
}

// ---------------------------------------------------------------------------
// Main edge kernel: one i, 64 j's per block. 256 threads: thread = (wave q, edge e),
// owns channels [q*32, q*32+32).
__global__ __launch_bounds__(256, 2) void edge_kernel(
    const float* __restrict__ A, const float* __restrict__ Bt,
    const float* __restrict__ RP, const float* __restrict__ W1,
    const float* __restrict__ W2, const float* __restrict__ b2,
    const float* __restrict__ W3, const float* __restrict__ b3,
    const float* __restrict__ g, const float* __restrict__ bb,
    const float* __restrict__ tp, const float* __restrict__ sp,
    const float* __restrict__ pm, float* __restrict__ out) {
    __shared__ float bufA[64 * NP];
    __shared__ float bufB[64 * NP];
    __shared__ float redS[4][64];
    __shared__ float redQ[4][64];

    const int i  = blockIdx.y;
    const int j0 = blockIdx.x * 64;
    const int t  = threadIdx.x;
    const int e  = t & 63;
    const int q  = t >> 6;
    const int j  = j0 + e;
    const int c0 = __builtin_amdgcn_readfirstlane(q) * 32;  // wave-uniform channel base

    // distogram bins for this edge (redundant across the 4 waves; cheap)
    float dx = tp[i * 3 + 0] - tp[j * 3 + 0];
    float dy = tp[i * 3 + 1] - tp[j * 3 + 1];
    float dz = tp[i * 3 + 2] - tp[j * 3 + 2];
    const int bd = bin_idx(sqrtf(dx * dx + dy * dy + dz * dz));
    dx = sp[i * 3 + 0] - sp[j * 3 + 0];
    dy = sp[i * 3 + 1] - sp[j * 3 + 1];
    dz = sp[i * 3 + 2] - sp[j * 3 + 2];
    const int bs = bin_idx(sqrtf(dx * dx + dy * dy + dz * dz));

    // ---- phase 1: assemble h1 = relu(A[i] + B[j] + RP[i-j] + WD[bin_d] + WS[bin_s]) ----
    const float4* Ai  = (const float4*)(A  + i * C_P + c0);
    const float4* Bj  = (const float4*)(Bt + j * C_P + c0);
    const float4* Rr  = (const float4*)(RP + (i - j + NRES - 1) * C_P + c0);
    const float4* Wd  = (const float4*)(W1 + (192 + (bd < 0 ? 0 : bd)) * C_P + c0);
    const float4* Wsb = (const float4*)(W1 + (214 + (bs < 0 ? 0 : bs)) * C_P + c0);
    const float fd = (bd < 0) ? 0.0f : 1.0f;
    const float fs = (bs < 0) ? 0.0f : 1.0f;
#pragma unroll
    for (int u = 0; u < 8; ++u) {
        float4 a = Ai[u], b = Bj[u], r = Rr[u], w = Wd[u], ws = Wsb[u];
        float v0 = a.x + b.x + r.x + fd * w.x + fs * ws.x;
        float v1 = a.y + b.y + r.y + fd * w.y + fs * ws.y;
        float v2 = a.z + b.z + r.z + fd * w.z + fs * ws.z;
        float v3 = a.w + b.w + r.w + fd * w.w + fs * ws.w;
        const int c = c0 + u * 4;
        bufA[e * NP + c + 0] = fmaxf(v0, 0.0f);
        bufA[e * NP + c + 1] = fmaxf(v1, 0.0f);
        bufA[e * NP + c + 2] = fmaxf(v2, 0.0f);
        bufA[e * NP + c + 3] = fmaxf(v3, 0.0f);
    }
    __syncthreads();

    // ---- phase 2: h2 = relu(h1 @ W2 + b2) ----
    float acc[32];
#pragma unroll
    for (int cc = 0; cc < 32; ++cc) acc[cc] = b2[c0 + cc];
    {
        const float* base = bufA + e * NP;
        for (int k = 0; k < C_P; ++k) {
            float h = base[k];
            const float* w = W2 + k * C_P + c0;  // wave-uniform address
#pragma unroll
            for (int cc = 0; cc < 32; ++cc) acc[cc] = fmaf(h, w[cc], acc[cc]);
        }
    }
#pragma unroll
    for (int cc = 0; cc < 32; ++cc) bufB[e * NP + c0 + cc] = fmaxf(acc[cc], 0.0f);
    __syncthreads();

    // ---- phase 3: h3 = h2 @ W3 + b3 ----
#pragma unroll
    for (int cc = 0; cc < 32; ++cc) acc[cc] = b3[c0 + cc];
    {
        const float* base = bufB + e * NP;
        for (int k = 0; k < C_P; ++k) {
            float h = base[k];
            const float* w = W3 + k * C_P + c0;  // wave-uniform address
#pragma unroll
            for (int cc = 0; cc < 32; ++cc) acc[cc] = fmaf(h, w[cc], acc[cc]);
        }
    }

    // ---- LayerNorm (two-pass, matches reference) ----
    float s1 = 0.0f;
#pragma unroll
    for (int cc = 0; cc < 32; ++cc) s1 += acc[cc];
    redS[q][e] = s1;
    __syncthreads();
    const float mu = (redS[0][e] + redS[1][e] + redS[2][e] + redS[3][e]) * (1.0f / 128.0f);
    float s2 = 0.0f;
#pragma unroll
    for (int cc = 0; cc < 32; ++cc) {
        float d0 = acc[cc] - mu;
        s2 += d0 * d0;
    }
    redQ[q][e] = s2;
    __syncthreads();
    const float var = (redQ[0][e] + redQ[1][e] + redQ[2][e] + redQ[3][e]) * (1.0f / 128.0f);
    const float inv = rsqrtf(var + 1e-5f);
    const float pmv = pm[i * NRES + j];

    // normalized values -> bufA (bufA free since post-layer2 sync)
#pragma unroll
    for (int cc = 0; cc < 32; ++cc) {
        const int c = c0 + cc;
        float y = (acc[cc] - mu) * inv * g[c] + bb[c];
        bufA[e * NP + c] = y * pmv;
    }
    __syncthreads();

    // ---- coalesced copy-out: block covers contiguous 64*128 floats ----
    const long long obase = ((long long)i * NRES + j0) * C_P;
#pragma unroll
    for (int r = 0; r < 32; ++r) {
        const int idx = t + r * 256;
        const int ee = idx >> 7;
        const int c  = idx & 127;
        out[obase + idx] = bufA[ee * NP + c];
    }
}

// ---------------------------------------------------------------------------
extern "C" void kernel_launch(void* const* d_in, const int* in_sizes, int n_in,
                              void* d_out, int out_size, void* d_ws, size_t ws_size,
                              hipStream_t stream) {
    const float* s    = (const float*)d_in[0];
    const float* tpos = (const float*)d_in[1];
    const float* scp  = (const float*)d_in[2];
    const float* pm   = (const float*)d_in[3];
    const float* dm   = (const float*)d_in[4];
    const float* W_sp = (const float*)d_in[5];
    const float* b_sp = (const float*)d_in[6];
    const float* W_rp = (const float*)d_in[7];
    const float* b_rp = (const float*)d_in[8];
    const float* W1   = (const float*)d_in[9];
    const float* b1   = (const float*)d_in[10];
    const float* W2   = (const float*)d_in[11];
    const float* b2   = (const float*)d_in[12];
    const float* W3   = (const float*)d_in[13];
    const float* b3   = (const float*)d_in[14];
    const float* g    = (const float*)d_in[15];
    const float* bb   = (const float*)d_in[16];
    float* out = (float*)d_out;

    float* ws    = (float*)d_ws;
    float* A     = ws;                       // 768*128
    float* Bt    = A + NRES * C_P;           // 768*128
    float* Wcomb = Bt + NRES * C_P;          // 65*128
    float* RP    = Wcomb + (FEAT + 1) * C_P; // 1535*128

    node_kernel<<<NRES, 128, 0, stream>>>(s, dm, W_sp, b_sp, W1, b1, A, Bt);
    wcomb_kernel<<<FEAT + 1, 128, 0, stream>>>(W_rp, b_rp, W1, Wcomb);
    rp_kernel<<<2 * NRES - 1, 128, 0, stream>>>(Wcomb, RP);
    edge_kernel<<<dim3(NRES / 64, NRES), 256, 0, stream>>>(
        A, Bt, RP, W1, W2, b2, W3, b3, g, bb, tpos, scp, pm, out);
}

// Round 3
// 263.383 us; speedup vs baseline: 2.4674x; 2.4674x over previous
//
#include <hip/hip_runtime.h>
#include <hip/hip_bf16.h>

#define NRES   768
#define C_S    256
#define C_P    128
#define FEAT   64
#define NTILES (NRES * (NRES / 64))   // 9216

typedef float f32x4 __attribute__((ext_vector_type(4)));
typedef short s16x8 __attribute__((ext_vector_type(8)));
typedef short s16x4 __attribute__((ext_vector_type(4)));

__device__ __forceinline__ short to_bf16(float f) {
    unsigned u = __builtin_bit_cast(unsigned, f);
    u += 0x7fffu + ((u >> 16) & 1u);   // RNE
    return (short)(u >> 16);
}

// ---------------------------------------------------------------------------
__device__ __forceinline__ int bin_idx(float d) {
    const float lo0  = 0.001f;
    const float step = (20.0f - 0.001f) / 21.0f;
    int k = (int)floorf((d - lo0) / step);
    if (k < -1) k = -1;
    if (k > 21) k = 21;
    for (int kk = k + 1; kk >= k - 1; --kk) {
        if (kk < 0 || kk > 21) continue;
        float lk = lo0 + (float)kk * step;
        float uk = (kk < 21) ? (lo0 + (float)(kk + 1) * step) : 1e8f;
        if (d > lk && d < uk) return kk;
    }
    return -1;
}

// ---------------------------------------------------------------------------
__global__ void node_kernel(const float* __restrict__ s, const float* __restrict__ dm,
                            const float* __restrict__ W_sp, const float* __restrict__ b_sp,
                            const float* __restrict__ W1, const float* __restrict__ b1,
                            float* __restrict__ A, float* __restrict__ Bt) {
    __shared__ float srow[C_S];
    __shared__ float psh[FEAT];
    const int i = blockIdx.x;
    const int t = threadIdx.x;  // 128 threads
    srow[t]       = s[i * C_S + t];
    srow[t + 128] = s[i * C_S + 128 + t];
    __syncthreads();
    if (t < FEAT) {
        float acc = b_sp[t];
        for (int m = 0; m < C_S; ++m) acc = fmaf(srow[m], W_sp[m * FEAT + t], acc);
        psh[t] = acc;
    }
    __syncthreads();
    const float d = dm[i];
    float accA = fmaf(d, W1[236 * C_P + t], b1[t]);
    float accB = d * W1[237 * C_P + t];
    for (int k = 0; k < FEAT; ++k) {
        float p = psh[k];
        accA = fmaf(p, W1[k * C_P + t], accA);
        accB = fmaf(p, W1[(FEAT + k) * C_P + t], accB);
    }
    A[i * C_P + t]  = accA;
    Bt[i * C_P + t] = accB;
}

// ---------------------------------------------------------------------------
__global__ void wcomb_kernel(const float* __restrict__ W_rp, const float* __restrict__ b_rp,
                             const float* __restrict__ W1, float* __restrict__ Wcomb) {
    const int k = blockIdx.x;   // 0..64
    const int c = threadIdx.x;  // 128
    float acc = 0.0f;
    if (k < FEAT) {
        for (int m = 0; m < FEAT; ++m)
            acc = fmaf(W_rp[k * FEAT + m], W1[(2 * FEAT + m) * C_P + c], acc);
    } else {
        for (int m = 0; m < FEAT; ++m)
            acc = fmaf(b_rp[m], W1[(2 * FEAT + m) * C_P + c], acc);
    }
    Wcomb[k * C_P + c] = acc;
}

// ---------------------------------------------------------------------------
__global__ void rp_kernel(const float* __restrict__ Wcomb, float* __restrict__ RP) {
    __shared__ float emb[FEAT];
    const int bi = blockIdx.x;            // 0..1534
    const float d = (float)(bi - (NRES - 1));
    const int c = threadIdx.x;            // 128
    if (c < FEAT / 2) {
        float expo = 2.0f * (float)c / (float)FEAT;
        float freq = 3.14159265358979323846f / powf(2056.0f, expo);
        float ang = d * freq;
        emb[c]            = sinf(ang);
        emb[c + FEAT / 2] = cosf(ang);
    }
    __syncthreads();
    float acc = Wcomb[FEAT * C_P + c];
    for (int k = 0; k < FEAT; ++k) acc = fmaf(emb[k], Wcomb[k * C_P + c], acc);
    RP[bi * C_P + c] = acc;
}

// ---------------------------------------------------------------------------
// Transpose W2,W3 to [n][k] bf16 so MFMA A-frag (weight) reads are contiguous in k.
__global__ void wt_kernel(const float* __restrict__ W2, const float* __restrict__ W3,
                          short* __restrict__ Wt2, short* __restrict__ Wt3) {
    const int n = blockIdx.x & 127;
    const int k = threadIdx.x;
    if (blockIdx.x < 128) Wt2[n * C_P + k] = to_bf16(W2[k * C_P + n]);
    else                  Wt3[n * C_P + k] = to_bf16(W3[k * C_P + n]);
}

// ---------------------------------------------------------------------------
// Persistent edge kernel. Per tile: i fixed, 64 j's. 4 waves; wave q owns output
// channels [q*32, q*32+32). GEMMs computed transposed: D'[n][e] = mfma(Wt, h).
__global__ __launch_bounds__(256, 2) void edge_kernel(
    const float* __restrict__ A, const float* __restrict__ Bt,
    const float* __restrict__ RP, const float* __restrict__ W1,
    const short* __restrict__ Wt2, const short* __restrict__ Wt3,
    const float* __restrict__ b2, const float* __restrict__ b3,
    const float* __restrict__ lng, const float* __restrict__ lnb,
    const float* __restrict__ tp, const float* __restrict__ sp,
    const float* __restrict__ pm, float* __restrict__ out)
{
    __shared__ short h1s[64 * C_P];   // bf16, XOR-swizzled rows
    __shared__ short h2s[64 * C_P];
    __shared__ float redS[64 * 4];    // [e][wave]

    const int t    = threadIdx.x;
    const int lane = t & 63;
    const int q    = t >> 6;     // wave id
    const int m    = lane & 15;  // row-in-tile index for MFMA frags
    const int kg   = lane >> 4;  // k-group

    // ---- hoisted weight fragments (stay in VGPRs across all tiles) ----
    s16x8 wf2[2][4], wf3[2][4];
#pragma unroll
    for (int nt = 0; nt < 2; ++nt) {
        const int n = q * 32 + nt * 16 + m;
#pragma unroll
        for (int ks = 0; ks < 4; ++ks) {
            const int k = ks * 32 + kg * 8;
            wf2[nt][ks] = *(const s16x8*)(Wt2 + n * C_P + k);
            wf3[nt][ks] = *(const s16x8*)(Wt3 + n * C_P + k);
        }
    }
    f32x4 b2f[2], b3f[2], gf[2], bbf[2];
#pragma unroll
    for (int nt = 0; nt < 2; ++nt) {
        const int n4 = q * 32 + nt * 16 + kg * 4;
        b2f[nt] = *(const f32x4*)(b2  + n4);
        b3f[nt] = *(const f32x4*)(b3  + n4);
        gf[nt]  = *(const f32x4*)(lng + n4);
        bbf[nt] = *(const f32x4*)(lnb + n4);
    }

    for (int tile = blockIdx.x; tile < NTILES; tile += gridDim.x) {
        const int i  = tile / 12;
        const int j0 = (tile % 12) * 64;

        // ---------- phase 1: assemble h1 (bf16, swizzled) ----------
        {
            const int e = lane;
            const int j = j0 + e;
            const int c0 = q * 32;
            float dx = tp[i*3+0] - tp[j*3+0];
            float dy = tp[i*3+1] - tp[j*3+1];
            float dz = tp[i*3+2] - tp[j*3+2];
            const int bd = bin_idx(sqrtf(dx*dx + dy*dy + dz*dz));
            dx = sp[i*3+0] - sp[j*3+0];
            dy = sp[i*3+1] - sp[j*3+1];
            dz = sp[i*3+2] - sp[j*3+2];
            const int bs = bin_idx(sqrtf(dx*dx + dy*dy + dz*dz));
            const float4* Ai  = (const float4*)(A  + i * C_P + c0);
            const float4* Bj  = (const float4*)(Bt + j * C_P + c0);
            const float4* Rr  = (const float4*)(RP + (i - j + NRES - 1) * C_P + c0);
            const float4* Wd  = (const float4*)(W1 + (192 + (bd < 0 ? 0 : bd)) * C_P + c0);
            const float4* Wsb = (const float4*)(W1 + (214 + (bs < 0 ? 0 : bs)) * C_P + c0);
            const float fd = (bd < 0) ? 0.0f : 1.0f;
            const float fs = (bs < 0) ? 0.0f : 1.0f;
            float v[32];
#pragma unroll
            for (int u = 0; u < 8; ++u) {
                float4 a = Ai[u], b = Bj[u], r = Rr[u], w = Wd[u], ws2 = Wsb[u];
                v[u*4+0] = fmaxf(a.x + b.x + r.x + fd*w.x + fs*ws2.x, 0.0f);
                v[u*4+1] = fmaxf(a.y + b.y + r.y + fd*w.y + fs*ws2.y, 0.0f);
                v[u*4+2] = fmaxf(a.z + b.z + r.z + fd*w.z + fs*ws2.z, 0.0f);
                v[u*4+3] = fmaxf(a.w + b.w + r.w + fd*w.w + fs*ws2.w, 0.0f);
            }
#pragma unroll
            for (int w8 = 0; w8 < 4; ++w8) {
                s16x8 pk;
#pragma unroll
                for (int u = 0; u < 8; ++u) pk[u] = to_bf16(v[w8*8+u]);
                const int byt = (e * 256 + (c0 + w8 * 8) * 2) ^ ((e & 15) << 4);
                *(s16x8*)((char*)h1s + byt) = pk;
            }
        }
        __syncthreads();

        // ---------- layer 2: h2' = relu(W2^T · h1^T + b2) via MFMA ----------
        f32x4 acc[2][4];
#pragma unroll
        for (int nt = 0; nt < 2; ++nt)
#pragma unroll
            for (int et = 0; et < 4; ++et) acc[nt][et] = b2f[nt];
#pragma unroll
        for (int ks = 0; ks < 4; ++ks) {
#pragma unroll
            for (int et = 0; et < 4; ++et) {
                const int e = et * 16 + m;
                const int byt = (e * 256 + (ks * 32 + kg * 8) * 2) ^ (m << 4);
                s16x8 hf = *(const s16x8*)((const char*)h1s + byt);
                acc[0][et] = __builtin_amdgcn_mfma_f32_16x16x32_bf16(wf2[0][ks], hf, acc[0][et], 0, 0, 0);
                acc[1][et] = __builtin_amdgcn_mfma_f32_16x16x32_bf16(wf2[1][ks], hf, acc[1][et], 0, 0, 0);
            }
        }
#pragma unroll
        for (int nt = 0; nt < 2; ++nt) {
            const int nb = (q * 32 + nt * 16 + kg * 4) * 2;  // byte offset of channel in row
#pragma unroll
            for (int et = 0; et < 4; ++et) {
                const int e = et * 16 + m;
                s16x4 pk;
#pragma unroll
                for (int r = 0; r < 4; ++r) pk[r] = to_bf16(fmaxf(acc[nt][et][r], 0.0f));
                const int byt = (e * 256 + nb) ^ (m << 4);
                *(s16x4*)((char*)h2s + byt) = pk;
            }
        }
        __syncthreads();

        // ---------- layer 3: h3' = W3^T · h2^T + b3 ----------
        f32x4 acc3[2][4];
#pragma unroll
        for (int nt = 0; nt < 2; ++nt)
#pragma unroll
            for (int et = 0; et < 4; ++et) acc3[nt][et] = b3f[nt];
#pragma unroll
        for (int ks = 0; ks < 4; ++ks) {
#pragma unroll
            for (int et = 0; et < 4; ++et) {
                const int e = et * 16 + m;
                const int byt = (e * 256 + (ks * 32 + kg * 8) * 2) ^ (m << 4);
                s16x8 hf = *(const s16x8*)((const char*)h2s + byt);
                acc3[0][et] = __builtin_amdgcn_mfma_f32_16x16x32_bf16(wf3[0][ks], hf, acc3[0][et], 0, 0, 0);
                acc3[1][et] = __builtin_amdgcn_mfma_f32_16x16x32_bf16(wf3[1][ks], hf, acc3[1][et], 0, 0, 0);
            }
        }

        // ---------- LayerNorm (two-pass, matches reference) ----------
        float part[4];
#pragma unroll
        for (int et = 0; et < 4; ++et) {
            float s0 = 0.0f;
#pragma unroll
            for (int nt = 0; nt < 2; ++nt)
#pragma unroll
                for (int r = 0; r < 4; ++r) s0 += acc3[nt][et][r];
            s0 += __shfl_xor(s0, 16);
            s0 += __shfl_xor(s0, 32);
            part[et] = s0;
        }
        {
            float myv = (kg == 0) ? part[0] : (kg == 1) ? part[1] : (kg == 2) ? part[2] : part[3];
            redS[(kg * 16 + m) * 4 + q] = myv;
        }
        __syncthreads();
        float mu[4];
#pragma unroll
        for (int et = 0; et < 4; ++et) {
            f32x4 vv = *(const f32x4*)&redS[(et * 16 + m) * 4];
            mu[et] = (vv[0] + vv[1] + vv[2] + vv[3]) * (1.0f / 128.0f);
        }
        __syncthreads();
#pragma unroll
        for (int et = 0; et < 4; ++et) {
            float s0 = 0.0f;
#pragma unroll
            for (int nt = 0; nt < 2; ++nt)
#pragma unroll
                for (int r = 0; r < 4; ++r) {
                    float d0 = acc3[nt][et][r] - mu[et];
                    s0 += d0 * d0;
                }
            s0 += __shfl_xor(s0, 16);
            s0 += __shfl_xor(s0, 32);
            part[et] = s0;
        }
        {
            float myv = (kg == 0) ? part[0] : (kg == 1) ? part[1] : (kg == 2) ? part[2] : part[3];
            redS[(kg * 16 + m) * 4 + q] = myv;
        }
        __syncthreads();
        float inv[4];
#pragma unroll
        for (int et = 0; et < 4; ++et) {
            f32x4 vv = *(const f32x4*)&redS[(et * 16 + m) * 4];
            float var = (vv[0] + vv[1] + vv[2] + vv[3]) * (1.0f / 128.0f);
            inv[et] = rsqrtf(var + 1e-5f);
        }

        // ---------- scale/shift + mask + store (lane holds 4 contiguous ch) ----------
#pragma unroll
        for (int et = 0; et < 4; ++et) {
            const int e = et * 16 + m;
            const float pmv = pm[i * NRES + j0 + e];
#pragma unroll
            for (int nt = 0; nt < 2; ++nt) {
                f32x4 o;
#pragma unroll
                for (int r = 0; r < 4; ++r)
                    o[r] = ((acc3[nt][et][r] - mu[et]) * inv[et] * gf[nt][r] + bbf[nt][r]) * pmv;
                *(f32x4*)(out + ((size_t)(i * NRES + j0 + e)) * C_P + q * 32 + nt * 16 + kg * 4) = o;
            }
        }
        __syncthreads();   // protect h1s/h2s/redS for next tile
    }
}

// ---------------------------------------------------------------------------
extern "C" void kernel_launch(void* const* d_in, const int* in_sizes, int n_in,
                              void* d_out, int out_size, void* d_ws, size_t ws_size,
                              hipStream_t stream) {
    const float* s    = (const float*)d_in[0];
    const float* tpos = (const float*)d_in[1];
    const float* scp  = (const float*)d_in[2];
    const float* pm   = (const float*)d_in[3];
    const float* dm   = (const float*)d_in[4];
    const float* W_sp = (const float*)d_in[5];
    const float* b_sp = (const float*)d_in[6];
    const float* W_rp = (const float*)d_in[7];
    const float* b_rp = (const float*)d_in[8];
    const float* W1   = (const float*)d_in[9];
    const float* b1   = (const float*)d_in[10];
    const float* W2   = (const float*)d_in[11];
    const float* b2   = (const float*)d_in[12];
    const float* W3   = (const float*)d_in[13];
    const float* b3   = (const float*)d_in[14];
    const float* lng  = (const float*)d_in[15];
    const float* lnb  = (const float*)d_in[16];
    float* out = (float*)d_out;

    float* ws    = (float*)d_ws;
    float* A     = ws;                        // 768*128
    float* Bt    = A + NRES * C_P;            // 768*128
    float* Wcomb = Bt + NRES * C_P;           // 65*128
    float* RP    = Wcomb + (FEAT + 1) * C_P;  // 1535*128
    short* Wt2   = (short*)(RP + (2 * NRES - 1) * C_P);  // 128*128 bf16
    short* Wt3   = Wt2 + C_P * C_P;

    node_kernel<<<NRES, 128, 0, stream>>>(s, dm, W_sp, b_sp, W1, b1, A, Bt);
    wcomb_kernel<<<FEAT + 1, 128, 0, stream>>>(W_rp, b_rp, W1, Wcomb);
    rp_kernel<<<2 * NRES - 1, 128, 0, stream>>>(Wcomb, RP);
    wt_kernel<<<256, 128, 0, stream>>>(W2, W3, Wt2, Wt3);
    edge_kernel<<<512, 256, 0, stream>>>(A, Bt, RP, W1, Wt2, Wt3, b2, b3,
                                         lng, lnb, tpos, scp, pm, out);
}